// Round 5
// baseline (12028.027 us; speedup 1.0000x reference)
//
#include <hip/hip_runtime.h>
#include <hip/hip_bf16.h>
#include <math.h>

#define L_SEQ 4096
#define B_SZ 4
#define D_MODEL 512
#define D_INNER 1024
#define DT_RANK 32
#define D_STATE 16
#define M_ROWS (B_SZ * L_SEQ)   // 16384

typedef __hip_bfloat16 bf16;

// ---- scalar conversions ---------------------------------------------------
__device__ __forceinline__ float cvt_f(float v) { return v; }
__device__ __forceinline__ float cvt_f(bf16 v)  { return __bfloat162float(v); }
__device__ __forceinline__ void store_f(float* p, float v) { *p = v; }
__device__ __forceinline__ void store_f(bf16* p, float v)  { *p = __float2bfloat16(v); }

// ---- hardened transcendentals ---------------------------------------------
__device__ __forceinline__ float silu_f(float x) {
    const float xc = fminf(fmaxf(x, -60.0f), 60.0f);
    return x / (1.0f + __expf(-xc));
}
__device__ __forceinline__ float softplus_f(float x) {
    if (x > 20.0f) return x;
    if (x < -20.0f) return __expf(x);
    return log1pf(__expf(x));
}

// ---------------------------------------------------------------------------
// Generic "NT" GEMM, f32 accumulate: C[m,n] = sum_k A[m,k] * W[n,k]
// AMODE 1: A element = A[m,k] * silu(A2[m,k])   (fused gating for out_proj)
// EPI   1: C = softplus(C + bias[n])            (dt projection)
// Block 256 threads, tile BM x BN, BK=16, micro-tile TM x TN. All dims used
// here divide the tiles exactly, so no bounds checks. Scalar memory ops.
// ---------------------------------------------------------------------------
template<int BM, int BN, int TM, int TN, int AMODE, int EPI,
         class TA, class TW, class TC>
__global__ __launch_bounds__(256)
void gemm_nt(const TA* __restrict__ A, const TA* __restrict__ A2,
             const TW* __restrict__ W, const float* __restrict__ bias,
             TC* __restrict__ C, int K, int lda, int ldb, int ldc)
{
    constexpr int BK  = 16;
    constexpr int NTX = BN / TN;
    __shared__ float As[BK][BM + 4];
    __shared__ float Bs[BK][BN + 4];

    const int tid = threadIdx.x;
    const int tx  = tid % NTX;
    const int ty  = tid / NTX;
    const long row0 = (long)blockIdx.y * BM;
    const long col0 = (long)blockIdx.x * BN;

    float acc[TM][TN];
#pragma unroll
    for (int i = 0; i < TM; ++i)
#pragma unroll
        for (int j = 0; j < TN; ++j) acc[i][j] = 0.0f;

    const int lr = tid >> 2;          // 0..63
    const int lc = (tid & 3) << 2;    // 0,4,8,12

    for (int k0 = 0; k0 < K; k0 += BK) {
#pragma unroll
        for (int i = 0; i < BM / 64; ++i) {
            const int r = lr + i * 64;
            const long base = (row0 + r) * (long)lda + k0 + lc;
#pragma unroll
            for (int q = 0; q < 4; ++q) {
                float v = cvt_f(A[base + q]);
                if (AMODE == 1) v *= silu_f(cvt_f(A2[base + q]));
                As[lc + q][r] = v;
            }
        }
#pragma unroll
        for (int i = 0; i < BN / 64; ++i) {
            const int r = lr + i * 64;
            const long base = (col0 + r) * (long)ldb + k0 + lc;
#pragma unroll
            for (int q = 0; q < 4; ++q)
                Bs[lc + q][r] = cvt_f(W[base + q]);
        }
        __syncthreads();

#pragma unroll
        for (int k = 0; k < BK; ++k) {
            float a[TM], b[TN];
#pragma unroll
            for (int i = 0; i < TM; ++i) a[i] = As[k][ty * TM + i];
#pragma unroll
            for (int j = 0; j < TN; ++j) b[j] = Bs[k][tx * TN + j];
#pragma unroll
            for (int i = 0; i < TM; ++i)
#pragma unroll
                for (int j = 0; j < TN; ++j)
                    acc[i][j] = fmaf(a[i], b[j], acc[i][j]);
        }
        __syncthreads();
    }

#pragma unroll
    for (int i = 0; i < TM; ++i) {
        const long row = row0 + ty * TM + i;
#pragma unroll
        for (int j = 0; j < TN; ++j) {
            const long col = col0 + tx * TN + j;
            float v = acc[i][j];
            if (EPI == 1) v = softplus_f(v + bias[col]);
            store_f(C + row * ldc + col, v);
        }
    }
}

// ---------------------------------------------------------------------------
// Depthwise causal conv1d (k=4) + bias + SiLU. xz is bf16 workspace (lda
// 2048); w/bias are f32 inputs. rev=1: branch r operates in flipped-time
// coordinates; output xc is in scan order.
// ---------------------------------------------------------------------------
__global__ __launch_bounds__(256)
void conv_silu(const bf16* __restrict__ xz, const float* __restrict__ w,
               const float* __restrict__ bias, bf16* __restrict__ xc, int rev)
{
    const int idx = blockIdx.x * 256 + threadIdx.x;   // over M_ROWS * D_INNER
    const int d = idx & (D_INNER - 1);
    const int m = idx >> 10;
    const int b = m >> 12;             // L_SEQ = 4096
    const int t = m & (L_SEQ - 1);

    const bf16* xbase = xz + (size_t)b * L_SEQ * 2048 + d;
    float s = bias[d];
#pragma unroll
    for (int k = 0; k < 4; ++k) {
        const int src = t - 3 + k;
        if (src >= 0) {
            const int sm = rev ? (L_SEQ - 1 - src) : src;
            s += w[d * 4 + k] * __bfloat162float(xbase[(size_t)sm * 2048]);
        }
    }
    xc[idx] = __float2bfloat16(silu_f(s));
}

// ---------------------------------------------------------------------------
// Selective scan, one thread per (b, d, n). Alog/Dp are f32 inputs; dt/x/z/y
// are bf16 workspace; dbl is f32. Block 256 = 16 d x 16 n.
// ---------------------------------------------------------------------------
__global__ __launch_bounds__(256)
void scan_kernel(const bf16* __restrict__ dt_buf, const bf16* __restrict__ xc,
                 const float* __restrict__ dbl, const bf16* __restrict__ xz,
                 const float* __restrict__ Alog, const float* __restrict__ Dp,
                 bf16* __restrict__ yout, int rev, int acc)
{
    const int tid = threadIdx.x;
    const int n  = tid & 15;
    const int di = tid >> 4;
    const int d  = blockIdx.x * 16 + di;
    const int b  = blockIdx.y;

    const float Acoef = -__expf(Alog[d * D_STATE + n]);
    const float Dd = Dp[d];
    float h = 0.0f;

    const bf16*  dt_row = dt_buf + (size_t)b * L_SEQ * D_INNER + d;
    const bf16*  x_row  = xc     + (size_t)b * L_SEQ * D_INNER + d;
    const float* bl     = dbl    + (size_t)b * L_SEQ * 64;
    const bf16*  z_base = xz     + (size_t)b * L_SEQ * 2048 + D_INNER + d;
    bf16* y_base        = yout   + (size_t)b * L_SEQ * D_INNER + d;

    for (int t = 0; t < L_SEQ; ++t) {
        const float dt = __bfloat162float(dt_row[(size_t)t * D_INNER]);
        const float xv = __bfloat162float(x_row[(size_t)t * D_INNER]);
        const float Bv = bl[t * 64 + DT_RANK + n];
        const float Cv = bl[t * 64 + DT_RANK + D_STATE + n];

        const float a = __expf(fminf(dt * Acoef, 0.0f));   // a in (0,1]
        h = fmaf(a, h, dt * xv * Bv);
        h = fminf(fmaxf(h, -1e30f), 1e30f);                // scrub inf/NaN

        float p = h * Cv;
        p += __shfl_xor(p, 1, 64);
        p += __shfl_xor(p, 2, 64);
        p += __shfl_xor(p, 4, 64);
        p += __shfl_xor(p, 8, 64);

        if (n == 0) {
            const int tm = rev ? (L_SEQ - 1 - t) : t;
            const float z = __bfloat162float(z_base[(size_t)tm * 2048]);
            float y = (p + Dd * xv) * silu_f(z);
            const size_t oi = (size_t)tm * D_INNER;
            if (acc) y += __bfloat162float(y_base[oi]);
            y_base[oi] = __float2bfloat16(fminf(fmaxf(y, -1e30f), 1e30f));
        }
    }
}

// ---------------------------------------------------------------------------
extern "C" void kernel_launch(void* const* d_in, const int* in_sizes, int n_in,
                              void* d_out, int out_size, void* d_ws, size_t ws_size,
                              hipStream_t stream)
{
    // All inputs are f32 (per reference setup_inputs). Output is f32.
    const float* hs    = (const float*)d_in[0];
    const float* ahs   = (const float*)d_in[1];
    const float* in_w  = (const float*)d_in[2];
    const float* in_gw = (const float*)d_in[3];
    const float* convw[3] = {(const float*)d_in[4], (const float*)d_in[6], (const float*)d_in[8]};
    const float* convb[3] = {(const float*)d_in[5], (const float*)d_in[7], (const float*)d_in[9]};
    const float* xproj[3] = {(const float*)d_in[10], (const float*)d_in[11], (const float*)d_in[12]};
    const float* dtw[3]   = {(const float*)d_in[13], (const float*)d_in[15], (const float*)d_in[17]};
    const float* dtb[3]   = {(const float*)d_in[14], (const float*)d_in[16], (const float*)d_in[18]};
    const float* Alog[3]  = {(const float*)d_in[19], (const float*)d_in[20], (const float*)d_in[21]};
    const float* Dp[3]    = {(const float*)d_in[22], (const float*)d_in[23], (const float*)d_in[24]};
    const float* out_w = (const float*)d_in[25];

    // Workspace layout — 196 MB total (proven safe in rounds 3/4):
    //   regA : M*2048 bf16 = 64 MB  (axz for branch g, then xz for f/r)
    //   xc   : M*1024 bf16 = 32 MB
    //   dbl  : M*64   f32  =  4 MB
    //   dtB  : M*1024 bf16 = 32 MB
    //   yfr  : M*1024 bf16 = 32 MB
    //   yg   : M*1024 bf16 = 32 MB
    bf16*  regA = (bf16*)d_ws;
    bf16*  xc   = regA + (size_t)M_ROWS * 2048;
    float* dbl  = (float*)(xc + (size_t)M_ROWS * 1024);
    bf16*  dtB  = (bf16*)(dbl + (size_t)M_ROWS * 64);
    bf16*  yfr  = dtB + (size_t)M_ROWS * 1024;
    bf16*  yg   = yfr + (size_t)M_ROWS * 1024;

    const dim3 blk(256);
    const int order[3] = {2, 0, 1};   // g, f, r (regA holds axz first, then xz)

    // axz = ahs @ in_proj_g^T : (16384 x 512) @ (512 x 2048), f32 in -> bf16 ws
    gemm_nt<128,128,8,8,0,0><<<dim3(2048/128, M_ROWS/128), blk, 0, stream>>>(
        ahs, (const float*)nullptr, in_gw, (const float*)nullptr, regA,
        D_MODEL, D_MODEL, D_MODEL, 2048);

    for (int oi = 0; oi < 3; ++oi) {
        const int br = order[oi];
        const int rev  = (br == 1) ? 1 : 0;
        const int accf = (br == 1) ? 1 : 0;
        bf16* ybuf = (br == 2) ? yg : yfr;

        if (br == 0) {
            // regA now free (branch g done): xz = hs @ in_proj^T
            gemm_nt<128,128,8,8,0,0><<<dim3(2048/128, M_ROWS/128), blk, 0, stream>>>(
                hs, (const float*)nullptr, in_w, (const float*)nullptr, regA,
                D_MODEL, D_MODEL, D_MODEL, 2048);
        }

        conv_silu<<<dim3((M_ROWS * D_INNER) / 256), blk, 0, stream>>>(
            regA, convw[br], convb[br], xc, rev);

        // dbl = xc @ xproj^T : (16384 x 1024) @ (1024 x 64) -> f32
        gemm_nt<64,64,4,4,0,0><<<dim3(1, M_ROWS/64), blk, 0, stream>>>(
            xc, (const bf16*)nullptr, xproj[br], (const float*)nullptr, dbl,
            D_INNER, D_INNER, D_INNER, 64);

        // dt = softplus(dbl[:, :32] @ dtw^T + dtb) : (16384 x 32) @ (32 x 1024)
        gemm_nt<128,128,8,8,0,1><<<dim3(1024/128, M_ROWS/128), blk, 0, stream>>>(
            dbl, (const float*)nullptr, dtw[br], dtb[br], dtB,
            DT_RANK, 64, DT_RANK, D_INNER);

        scan_kernel<<<dim3(D_INNER/16, B_SZ), blk, 0, stream>>>(
            dtB, xc, dbl, regA, Alog[br], Dp[br], ybuf, rev, accf);
    }

    // out = ((y_f + y_r) * silu(y_g)) @ out_proj^T : (16384 x 1024) @ (1024 x 512)
    gemm_nt<128,128,8,8,1,0><<<dim3(512/128, M_ROWS/128), blk, 0, stream>>>(
        yfr, yg, out_w, (const float*)nullptr, (float*)d_out,
        D_INNER, D_INNER, D_INNER, D_MODEL);
}

// Round 6
// 2278.717 us; speedup vs baseline: 5.2784x; 5.2784x over previous
//
#include <hip/hip_runtime.h>
#include <hip/hip_bf16.h>
#include <math.h>

#define L_SEQ 4096
#define B_SZ 4
#define D_MODEL 512
#define D_INNER 1024
#define DT_RANK 32
#define D_STATE 16
#define M_ROWS (B_SZ * L_SEQ)   // 16384
#define NC 64                    // chunks per sequence
#define CHK (L_SEQ / NC)         // 64 steps per chunk

typedef __hip_bfloat16 bf16;
struct b4 { bf16 x, y, z, w; };

// ---- conversions ----------------------------------------------------------
__device__ __forceinline__ float cvt_f(float v) { return v; }
__device__ __forceinline__ float cvt_f(bf16 v)  { return __bfloat162float(v); }
__device__ __forceinline__ void store_f(float* p, float v) { *p = v; }
__device__ __forceinline__ void store_f(bf16* p, float v)  { *p = __float2bfloat16(v); }

__device__ __forceinline__ float4 load4f(const float* p) { return *(const float4*)p; }
__device__ __forceinline__ float4 load4f(const bf16* p) {
    const b4 t = *(const b4*)p;
    float4 v;
    v.x = __bfloat162float(t.x); v.y = __bfloat162float(t.y);
    v.z = __bfloat162float(t.z); v.w = __bfloat162float(t.w);
    return v;
}
__device__ __forceinline__ void store4f(float* p, float4 v) { *(float4*)p = v; }
__device__ __forceinline__ void store4f(bf16* p, float4 v) {
    b4 t;
    t.x = __float2bfloat16(v.x); t.y = __float2bfloat16(v.y);
    t.z = __float2bfloat16(v.z); t.w = __float2bfloat16(v.w);
    *(b4*)p = t;
}

// ---- hardened transcendentals ---------------------------------------------
__device__ __forceinline__ float silu_f(float x) {
    const float xc = fminf(fmaxf(x, -60.0f), 60.0f);
    return x / (1.0f + __expf(-xc));
}
__device__ __forceinline__ float softplus_f(float x) {
    if (x > 20.0f) return x;
    if (x < -20.0f) return __expf(x);
    return log1pf(__expf(x));
}

// ---------------------------------------------------------------------------
// Generic "NT" GEMM, f32 accumulate: C[m,n] = sum_k A[m,k] * W[n,k]
// AMODE 1: A element = A[m,k] * silu(A2[m,k])
// EPI   1: C = softplus(C + bias[n])
// ASTRIDE: physical element stride of A (2 = interleaved bf16 buffer)
// CSTRIDE: physical element stride of C
// ---------------------------------------------------------------------------
template<int BM, int BN, int TM, int TN, int AMODE, int EPI,
         int ASTRIDE, int CSTRIDE, class TA, class TW, class TC>
__global__ __launch_bounds__(256)
void gemm_nt(const TA* __restrict__ A, const TA* __restrict__ A2,
             const TW* __restrict__ W, const float* __restrict__ bias,
             TC* __restrict__ C, int K, int lda, int ldb, int ldc)
{
    constexpr int BK  = 16;
    constexpr int NTX = BN / TN;
    __shared__ float As[BK][BM + 4];
    __shared__ float Bs[BK][BN + 4];

    const int tid = threadIdx.x;
    const int tx  = tid % NTX;
    const int ty  = tid / NTX;
    const long row0 = (long)blockIdx.y * BM;
    const long col0 = (long)blockIdx.x * BN;

    float acc[TM][TN];
#pragma unroll
    for (int i = 0; i < TM; ++i)
#pragma unroll
        for (int j = 0; j < TN; ++j) acc[i][j] = 0.0f;

    const int lr = tid >> 2;          // 0..63
    const int lc = (tid & 3) << 2;    // 0,4,8,12

    for (int k0 = 0; k0 < K; k0 += BK) {
#pragma unroll
        for (int i = 0; i < BM / 64; ++i) {
            const int r = lr + i * 64;
            const long base = (row0 + r) * (long)lda + k0 + lc;
            float4 v;
            if (ASTRIDE == 1) {
                v = load4f(A + base);
                if (AMODE == 1) {
                    const float4 g = load4f(A2 + base);
                    v.x *= silu_f(g.x); v.y *= silu_f(g.y);
                    v.z *= silu_f(g.z); v.w *= silu_f(g.w);
                }
            } else {
                v.x = cvt_f(A[(base + 0) * ASTRIDE]);
                v.y = cvt_f(A[(base + 1) * ASTRIDE]);
                v.z = cvt_f(A[(base + 2) * ASTRIDE]);
                v.w = cvt_f(A[(base + 3) * ASTRIDE]);
            }
            As[lc + 0][r] = v.x; As[lc + 1][r] = v.y;
            As[lc + 2][r] = v.z; As[lc + 3][r] = v.w;
        }
#pragma unroll
        for (int i = 0; i < BN / 64; ++i) {
            const int r = lr + i * 64;
            const long base = (col0 + r) * (long)ldb + k0 + lc;
            const float4 v = load4f(W + base);
            Bs[lc + 0][r] = v.x; Bs[lc + 1][r] = v.y;
            Bs[lc + 2][r] = v.z; Bs[lc + 3][r] = v.w;
        }
        __syncthreads();

#pragma unroll
        for (int k = 0; k < BK; ++k) {
            float a[TM], b[TN];
#pragma unroll
            for (int i = 0; i < TM; ++i) a[i] = As[k][ty * TM + i];
#pragma unroll
            for (int j = 0; j < TN; ++j) b[j] = Bs[k][tx * TN + j];
#pragma unroll
            for (int i = 0; i < TM; ++i)
#pragma unroll
                for (int j = 0; j < TN; ++j)
                    acc[i][j] = fmaf(a[i], b[j], acc[i][j]);
        }
        __syncthreads();
    }

#pragma unroll
    for (int i = 0; i < TM; ++i) {
        const long row = row0 + ty * TM + i;
#pragma unroll
        for (int j = 0; j < TN; j += 4) {
            const long col = col0 + tx * TN + j;
            float4 v;
            v.x = acc[i][j]; v.y = acc[i][j + 1];
            v.z = acc[i][j + 2]; v.w = acc[i][j + 3];
            if (EPI == 1) {
                v.x = softplus_f(v.x + bias[col + 0]);
                v.y = softplus_f(v.y + bias[col + 1]);
                v.z = softplus_f(v.z + bias[col + 2]);
                v.w = softplus_f(v.w + bias[col + 3]);
            }
            const long cb = row * (long)ldc + col;
            if (CSTRIDE == 1) {
                store4f(C + cb, v);
            } else {
                store_f(C + (cb + 0) * CSTRIDE, v.x);
                store_f(C + (cb + 1) * CSTRIDE, v.y);
                store_f(C + (cb + 2) * CSTRIDE, v.z);
                store_f(C + (cb + 3) * CSTRIDE, v.w);
            }
        }
    }
}

// ---------------------------------------------------------------------------
// Depthwise causal conv1d (k=4) + bias + SiLU -> x slot of interleaved dx
// buffer (dx[...,1], element stride 2). rev=1: flipped-time read.
// ---------------------------------------------------------------------------
__global__ __launch_bounds__(256)
void conv_silu(const bf16* __restrict__ xz, const float* __restrict__ w,
               const float* __restrict__ bias, bf16* __restrict__ dx, int rev)
{
    const int idx = blockIdx.x * 256 + threadIdx.x;   // over M_ROWS * D_INNER
    const int d = idx & (D_INNER - 1);
    const int m = idx >> 10;
    const int b = m >> 12;
    const int t = m & (L_SEQ - 1);

    const bf16* xbase = xz + (size_t)b * L_SEQ * 2048 + d;
    float s = bias[d];
#pragma unroll
    for (int k = 0; k < 4; ++k) {
        const int src = t - 3 + k;
        if (src >= 0) {
            const int sm = rev ? (L_SEQ - 1 - src) : src;
            s += w[d * 4 + k] * __bfloat162float(xbase[(size_t)sm * 2048]);
        }
    }
    dx[(size_t)idx * 2 + 1] = __float2bfloat16(silu_f(s));
}

// ---------------------------------------------------------------------------
// Chunked selective scan, phase A: per (b,chunk,d) evolve h[16] from 0 over
// CHK steps; emit chunk-final hF[b,c,d,n] and S = sum(dt) (decay exponent).
// Block 1024 = one thread per d. Grid (NC, B).
// ---------------------------------------------------------------------------
__global__ __launch_bounds__(1024)
void scan_a(const unsigned int* __restrict__ dx, const float* __restrict__ dbl,
            const float* __restrict__ Alog, float* __restrict__ hF,
            float* __restrict__ Ssum)
{
    const int d = threadIdx.x;
    const int c = blockIdx.x;
    const int b = blockIdx.y;

    __shared__ float Bsh[CHK][16];
    {
        const int tl = d >> 4, nl = d & 15;
        Bsh[tl][nl] = dbl[((size_t)b * L_SEQ + c * CHK + tl) * 64 + DT_RANK + nl];
    }
    __syncthreads();

    float Acoef[16];
#pragma unroll
    for (int n = 0; n < 16; ++n) Acoef[n] = -__expf(Alog[d * 16 + n]);

    float h[16];
#pragma unroll
    for (int n = 0; n < 16; ++n) h[n] = 0.0f;
    float S = 0.0f;

    const unsigned int* dxp = dx + ((size_t)b * L_SEQ + c * CHK) * 1024 + d;
    unsigned int v = dxp[0];
    for (int t = 0; t < CHK; ++t) {
        const unsigned int vn = (t + 1 < CHK) ? dxp[(size_t)(t + 1) * 1024] : 0u;
        const float dt = __uint_as_float(v << 16);
        const float xv = __uint_as_float(v & 0xffff0000u);
        S += dt;
        const float dtx = dt * xv;
#pragma unroll
        for (int n = 0; n < 16; ++n)
            h[n] = fmaf(__expf(dt * Acoef[n]), h[n], dtx * Bsh[t][n]);
        v = vn;
    }

    float* hp = hF + (((size_t)(b * NC + c) * 1024 + d) << 4);
#pragma unroll
    for (int n = 0; n < 16; ++n) hp[n] = h[n];
    Ssum[(size_t)(b * NC + c) * 1024 + d] = S;
}

// ---------------------------------------------------------------------------
// Phase B: sequential combine over chunks. Thread per (b,d,n), n fastest.
// In-place: hF[b,c,d,n] becomes the chunk's TRUE initial state.
// ---------------------------------------------------------------------------
__global__ __launch_bounds__(256)
void scan_b(float* __restrict__ hF, const float* __restrict__ Ssum,
            const float* __restrict__ Alog)
{
    const int idx = blockIdx.x * 256 + threadIdx.x;   // B*D*16
    const int n  = idx & 15;
    const int dn = idx >> 4;
    const int d  = dn & (D_INNER - 1);
    const int b  = dn >> 10;

    const float Acoef = -__expf(Alog[d * 16 + n]);
    float H = 0.0f;
    for (int c = 0; c < NC; ++c) {
        const size_t base = (size_t)(b * NC + c) * 1024 + d;
        const float S = Ssum[base];
        float* hp = hF + (base << 4) + n;
        const float hOld = *hp;
        *hp = H;                                   // h_init for chunk c
        H = fmaf(__expf(Acoef * S), H, hOld);      // state at end of chunk c
    }
}

// ---------------------------------------------------------------------------
// Phase C: re-run each chunk from its true h_init; emit y with fused
// D*x + silu(z) gating, written at original time order (rev maps back).
// acc=1: accumulate into yout (branch r folds into branch f's buffer).
// ---------------------------------------------------------------------------
__global__ __launch_bounds__(1024)
void scan_c(const unsigned int* __restrict__ dx, const float* __restrict__ dbl,
            const float* __restrict__ hF, const float* __restrict__ Alog,
            const float* __restrict__ Dp, const bf16* __restrict__ xz,
            bf16* __restrict__ yout, int rev, int acc)
{
    const int d = threadIdx.x;
    const int c = blockIdx.x;
    const int b = blockIdx.y;

    __shared__ float Bsh[CHK][16];
    __shared__ float Csh[CHK][16];
    {
        const int tl = d >> 4, nl = d & 15;
        const size_t rb = ((size_t)b * L_SEQ + c * CHK + tl) * 64;
        Bsh[tl][nl] = dbl[rb + DT_RANK + nl];
        Csh[tl][nl] = dbl[rb + DT_RANK + D_STATE + nl];
    }
    __syncthreads();

    float Acoef[16];
#pragma unroll
    for (int n = 0; n < 16; ++n) Acoef[n] = -__expf(Alog[d * 16 + n]);
    const float Dd = Dp[d];

    float h[16];
    {
        const float* hp = hF + (((size_t)(b * NC + c) * 1024 + d) << 4);
#pragma unroll
        for (int n = 0; n < 16; ++n) h[n] = hp[n];
    }

    const unsigned int* dxp = dx + ((size_t)b * L_SEQ + c * CHK) * 1024 + d;
    const bf16* z_base = xz + (size_t)b * L_SEQ * 2048 + D_INNER + d;
    bf16* y_base = yout + (size_t)b * L_SEQ * D_INNER + d;

    unsigned int v = dxp[0];
    for (int t = 0; t < CHK; ++t) {
        const unsigned int vn = (t + 1 < CHK) ? dxp[(size_t)(t + 1) * 1024] : 0u;
        const float dt = __uint_as_float(v << 16);
        const float xv = __uint_as_float(v & 0xffff0000u);
        const float dtx = dt * xv;
        float y = 0.0f;
#pragma unroll
        for (int n = 0; n < 16; ++n) {
            h[n] = fmaf(__expf(dt * Acoef[n]), h[n], dtx * Bsh[t][n]);
            y = fmaf(h[n], Csh[t][n], y);
        }
        const int tg = c * CHK + t;
        const int tm = rev ? (L_SEQ - 1 - tg) : tg;
        const float z = __bfloat162float(z_base[(size_t)tm * 2048]);
        float yo = (y + Dd * xv) * silu_f(z);
        const size_t oi = (size_t)tm * D_INNER;
        if (acc) yo += __bfloat162float(y_base[oi]);
        y_base[oi] = __float2bfloat16(yo);
        v = vn;
    }
}

// ---------------------------------------------------------------------------
extern "C" void kernel_launch(void* const* d_in, const int* in_sizes, int n_in,
                              void* d_out, int out_size, void* d_ws, size_t ws_size,
                              hipStream_t stream)
{
    const float* hs    = (const float*)d_in[0];
    const float* ahs   = (const float*)d_in[1];
    const float* in_w  = (const float*)d_in[2];
    const float* in_gw = (const float*)d_in[3];
    const float* convw[3] = {(const float*)d_in[4], (const float*)d_in[6], (const float*)d_in[8]};
    const float* convb[3] = {(const float*)d_in[5], (const float*)d_in[7], (const float*)d_in[9]};
    const float* xproj[3] = {(const float*)d_in[10], (const float*)d_in[11], (const float*)d_in[12]};
    const float* dtw[3]   = {(const float*)d_in[13], (const float*)d_in[15], (const float*)d_in[17]};
    const float* dtb[3]   = {(const float*)d_in[14], (const float*)d_in[16], (const float*)d_in[18]};
    const float* Alog[3]  = {(const float*)d_in[19], (const float*)d_in[20], (const float*)d_in[21]};
    const float* Dp[3]    = {(const float*)d_in[22], (const float*)d_in[23], (const float*)d_in[24]};
    const float* out_w = (const float*)d_in[25];

    // Workspace (~214 MB):
    //   regA : M*2048 bf16 = 64 MB   (axz for branch g, then xz for f/r)
    //   dbl  : M*64   f32  =  4 MB
    //   dx   : M*1024 u32  = 64 MB   (interleaved bf16 {dt, x})
    //   yfr  : M*1024 bf16 = 32 MB
    //   yg   : M*1024 bf16 = 32 MB
    //   hF   : B*NC*1024*16 f32 = 16.8 MB
    //   Ssum : B*NC*1024 f32    =  1 MB
    bf16*  regA = (bf16*)d_ws;
    float* dbl  = (float*)(regA + (size_t)M_ROWS * 2048);
    bf16*  dx   = (bf16*)(dbl + (size_t)M_ROWS * 64);
    bf16*  yfr  = dx + (size_t)M_ROWS * 2048;
    bf16*  yg   = yfr + (size_t)M_ROWS * 1024;
    float* hF   = (float*)(yg + (size_t)M_ROWS * 1024);
    float* Ssum = hF + (size_t)B_SZ * NC * 1024 * 16;
    unsigned int* dxu = (unsigned int*)dx;

    const dim3 blk(256);
    const int order[3] = {2, 0, 1};   // g, f, r (regA holds axz first, then xz)

    // axz = ahs @ in_proj_g^T : (16384 x 512) @ (512 x 2048)
    gemm_nt<128,128,8,8,0,0,1,1><<<dim3(16, 128), blk, 0, stream>>>(
        ahs, (const float*)nullptr, in_gw, (const float*)nullptr, regA,
        D_MODEL, D_MODEL, D_MODEL, 2048);

    for (int oi = 0; oi < 3; ++oi) {
        const int br = order[oi];
        const int rev  = (br == 1) ? 1 : 0;
        const int accf = (br == 1) ? 1 : 0;
        bf16* ybuf = (br == 2) ? yg : yfr;

        if (br == 0) {
            // regA free (branch g fully consumed): xz = hs @ in_proj^T
            gemm_nt<128,128,8,8,0,0,1,1><<<dim3(16, 128), blk, 0, stream>>>(
                hs, (const float*)nullptr, in_w, (const float*)nullptr, regA,
                D_MODEL, D_MODEL, D_MODEL, 2048);
        }

        // conv + silu -> dx x-slot (scan order)
        conv_silu<<<dim3((M_ROWS * D_INNER) / 256), blk, 0, stream>>>(
            regA, convw[br], convb[br], dx, rev);

        // dbl = x @ xproj^T : (16384 x 1024) @ (1024 x 64); A = dx x-slot, stride 2
        gemm_nt<64,64,4,4,0,0,2,1><<<dim3(1, 256), blk, 0, stream>>>(
            dx + 1, (const bf16*)nullptr, xproj[br], (const float*)nullptr, dbl,
            D_INNER, D_INNER, D_INNER, 64);

        // dt = softplus(dbl[:, :32] @ dtw^T + dtb) -> dx dt-slot (stride 2)
        gemm_nt<128,128,8,8,0,1,1,2><<<dim3(8, 128), blk, 0, stream>>>(
            dbl, (const float*)nullptr, dtw[br], dtb[br], dx,
            DT_RANK, 64, DT_RANK, D_INNER);

        // chunked selective scan
        scan_a<<<dim3(NC, B_SZ), dim3(1024), 0, stream>>>(dxu, dbl, Alog[br], hF, Ssum);
        scan_b<<<dim3((B_SZ * D_INNER * 16) / 256), blk, 0, stream>>>(hF, Ssum, Alog[br]);
        scan_c<<<dim3(NC, B_SZ), dim3(1024), 0, stream>>>(
            dxu, dbl, hF, Alog[br], Dp[br], regA, ybuf, rev, accf);
    }

    // out = ((y_f + y_r) * silu(y_g)) @ out_proj^T : (16384 x 1024) @ (1024 x 512)
    gemm_nt<128,128,8,8,1,0,1,1><<<dim3(4, 128), blk, 0, stream>>>(
        yfr, yg, out_w, (const float*)nullptr, (float*)d_out,
        D_INNER, D_INNER, D_INNER, D_MODEL);
}

// Round 7
// 1264.391 us; speedup vs baseline: 9.5129x; 1.8022x over previous
//
#include <hip/hip_runtime.h>
#include <hip/hip_bf16.h>
#include <math.h>

#define L_SEQ 4096
#define B_SZ 4
#define D_MODEL 512
#define D_INNER 1024
#define DT_RANK 32
#define D_STATE 16
#define M_ROWS (B_SZ * L_SEQ)   // 16384
#define NC 64                    // chunks per sequence
#define CHK (L_SEQ / NC)         // 64 steps per chunk

typedef __hip_bfloat16 bf16;
typedef __bf16 bf16x8 __attribute__((ext_vector_type(8)));
typedef float f32x4 __attribute__((ext_vector_type(4)));
struct us8 { ushort4 a, b; };    // 16-byte chunk of 8 bf16 bit patterns

// ---- bf16 bit conversions -------------------------------------------------
__device__ __forceinline__ unsigned short f2us(float f) {
    union { bf16 h; unsigned short u; } t;
    t.h = __float2bfloat16(f);
    return t.u;
}
__device__ __forceinline__ float us2f(unsigned short u) {
    union { bf16 h; unsigned short u; } t;
    t.u = u;
    return __bfloat162float(t.h);
}

// ---- hardened transcendentals ---------------------------------------------
__device__ __forceinline__ float silu_f(float x) {
    const float xc = fminf(fmaxf(x, -60.0f), 60.0f);
    return x / (1.0f + __expf(-xc));
}
__device__ __forceinline__ float softplus_f(float x) {
    if (x > 20.0f) return x;
    if (x < -20.0f) return __expf(x);
    return log1pf(__expf(x));
}

// ---------------------------------------------------------------------------
// f32 -> bf16 weight conversion (n divisible by 1024)
// ---------------------------------------------------------------------------
__global__ __launch_bounds__(256)
void cvt_bf16(const float* __restrict__ src, unsigned short* __restrict__ dst, int n)
{
    const int i = (blockIdx.x * 256 + threadIdx.x) * 4;
    if (i >= n) return;
    const float4 v = *(const float4*)(src + i);
    ushort4 o;
    o.x = f2us(v.x); o.y = f2us(v.y); o.z = f2us(v.z); o.w = f2us(v.w);
    *(ushort4*)(dst + i) = o;
}

// ---------------------------------------------------------------------------
// MFMA bf16 "NT" GEMM: C[m,n] = sum_k A[m,k] * W[n,k], f32 accumulate.
// mfma_f32_16x16x32_bf16; A-frag [m=lane&15][k=quad*8+j], B mirrored,
// C/D col=lane&15, row=quad*4+reg (m89/m120-verified layouts).
// SRCF: 0 = A bf16 (ushort), 1 = A f32 (convert in staging),
//       2 = A = hi-16 of u32 stream (x slot of packed dx), 3 = gated bf16
//       pair A*silu(A2).
// EPI : 0 none, 1 softplus(acc+bias[n]), 2 dual-write f32 C + bf16 C2 (n<32)
// CT  : 0 C bf16(ushort), 1 C f32.  CSTRIDE: phys elem stride of C.
// Block 256 = 4 waves; wave tile (WY*16) x (WX*16). LDS rows padded +8 bf16
// (stride 16B-aligned, 2-way-max bank aliasing = free on CDNA4).
// ---------------------------------------------------------------------------
template<int BM, int BN, int BK, int WY, int WX, int SRCF, int EPI, int CSTRIDE, int CT>
__global__ __launch_bounds__(256)
void gemm_mfma(const void* __restrict__ Ap, const void* __restrict__ A2p,
               const unsigned short* __restrict__ W, const float* __restrict__ bias,
               void* __restrict__ Cp, unsigned short* __restrict__ C2p,
               int K, int lda, int ldb, int ldc)
{
    constexpr int WGX = BN / (WX * 16);
    constexpr int WGY = BM / (WY * 16);
    static_assert(WGX * WGY == 4, "4 waves");
    constexpr int LDS_ROW = BK + 8;
    __shared__ unsigned short As[BM * LDS_ROW];
    __shared__ unsigned short Bs[BN * LDS_ROW];

    const int tid  = threadIdx.x;
    const int lane = tid & 63;
    const int wave = tid >> 6;
    const int wx = wave % WGX, wy = wave / WGX;
    const int l15 = lane & 15, quad = lane >> 4;
    const long row0 = (long)blockIdx.y * BM;
    const long col0 = (long)blockIdx.x * BN;

    f32x4 acc[WY][WX];
#pragma unroll
    for (int i = 0; i < WY; ++i)
#pragma unroll
        for (int j = 0; j < WX; ++j) acc[i][j] = (f32x4){0.f, 0.f, 0.f, 0.f};

    constexpr int NVA = BM * BK / 2048;   // 8-elem vectors per thread (A)
    constexpr int NVB = BN * BK / 2048;

    for (int k0 = 0; k0 < K; k0 += BK) {
        // ---- stage A ----
#pragma unroll
        for (int v = 0; v < NVA; ++v) {
            const int e = (v * 256 + tid) * 8;
            const int r = e / BK, c = e % BK;
            us8 t;
            if (SRCF == 0) {
                t = *(const us8*)((const unsigned short*)Ap + (row0 + r) * (long)lda + k0 + c);
            } else if (SRCF == 1) {
                const float* p = (const float*)Ap + (row0 + r) * (long)lda + k0 + c;
                const float4 f1 = *(const float4*)p;
                const float4 f2 = *(const float4*)(p + 4);
                t.a.x = f2us(f1.x); t.a.y = f2us(f1.y); t.a.z = f2us(f1.z); t.a.w = f2us(f1.w);
                t.b.x = f2us(f2.x); t.b.y = f2us(f2.y); t.b.z = f2us(f2.z); t.b.w = f2us(f2.w);
            } else if (SRCF == 2) {
                const unsigned int* p = (const unsigned int*)Ap + (row0 + r) * (long)lda + k0 + c;
                const uint4 u1 = *(const uint4*)p;
                const uint4 u2 = *(const uint4*)(p + 4);
                t.a.x = (unsigned short)(u1.x >> 16); t.a.y = (unsigned short)(u1.y >> 16);
                t.a.z = (unsigned short)(u1.z >> 16); t.a.w = (unsigned short)(u1.w >> 16);
                t.b.x = (unsigned short)(u2.x >> 16); t.b.y = (unsigned short)(u2.y >> 16);
                t.b.z = (unsigned short)(u2.z >> 16); t.b.w = (unsigned short)(u2.w >> 16);
            } else {
                const long off = (row0 + r) * (long)lda + k0 + c;
                const us8 ta = *(const us8*)((const unsigned short*)Ap + off);
                const us8 tg = *(const us8*)((const unsigned short*)A2p + off);
                t.a.x = f2us(us2f(ta.a.x) * silu_f(us2f(tg.a.x)));
                t.a.y = f2us(us2f(ta.a.y) * silu_f(us2f(tg.a.y)));
                t.a.z = f2us(us2f(ta.a.z) * silu_f(us2f(tg.a.z)));
                t.a.w = f2us(us2f(ta.a.w) * silu_f(us2f(tg.a.w)));
                t.b.x = f2us(us2f(ta.b.x) * silu_f(us2f(tg.b.x)));
                t.b.y = f2us(us2f(ta.b.y) * silu_f(us2f(tg.b.y)));
                t.b.z = f2us(us2f(ta.b.z) * silu_f(us2f(tg.b.z)));
                t.b.w = f2us(us2f(ta.b.w) * silu_f(us2f(tg.b.w)));
            }
            *(us8*)&As[r * LDS_ROW + c] = t;
        }
        // ---- stage B (weights, bf16) ----
#pragma unroll
        for (int v = 0; v < NVB; ++v) {
            const int e = (v * 256 + tid) * 8;
            const int r = e / BK, c = e % BK;
            *(us8*)&Bs[r * LDS_ROW + c] =
                *(const us8*)(W + (col0 + r) * (long)ldb + k0 + c);
        }
        __syncthreads();

#pragma unroll
        for (int kk = 0; kk < BK / 32; ++kk) {
            bf16x8 aF[WY], bF[WX];
#pragma unroll
            for (int i = 0; i < WY; ++i)
                aF[i] = *(const bf16x8*)&As[(wy * WY * 16 + i * 16 + l15) * LDS_ROW + kk * 32 + quad * 8];
#pragma unroll
            for (int j = 0; j < WX; ++j)
                bF[j] = *(const bf16x8*)&Bs[(wx * WX * 16 + j * 16 + l15) * LDS_ROW + kk * 32 + quad * 8];
#pragma unroll
            for (int i = 0; i < WY; ++i)
#pragma unroll
                for (int j = 0; j < WX; ++j)
                    acc[i][j] = __builtin_amdgcn_mfma_f32_16x16x32_bf16(
                        aF[i], bF[j], acc[i][j], 0, 0, 0);
        }
        __syncthreads();
    }

    // ---- epilogue: lane holds rows quad*4+r, col l15 of each 16x16 tile ----
#pragma unroll
    for (int i = 0; i < WY; ++i)
#pragma unroll
        for (int j = 0; j < WX; ++j) {
            const long mb = row0 + wy * WY * 16 + i * 16 + quad * 4;
            const long n  = col0 + wx * WX * 16 + j * 16 + l15;
            const float bv = (EPI == 1) ? bias[n] : 0.0f;
#pragma unroll
            for (int r = 0; r < 4; ++r) {
                float val = acc[i][j][r];
                if (EPI == 1) val = softplus_f(val + bv);
                const long off = (mb + r) * (long)ldc + n;
                if (CT == 0) ((unsigned short*)Cp)[off * CSTRIDE] = f2us(val);
                else         ((float*)Cp)[off * CSTRIDE] = val;
                if (EPI == 2 && n < DT_RANK) C2p[(mb + r) * DT_RANK + n] = f2us(val);
            }
        }
}

// ---------------------------------------------------------------------------
// Depthwise causal conv1d (k=4) + bias + SiLU -> x slot of packed dx buffer
// (dx bf16 elem 2*idx+1). rev=1: flipped-time read.
// ---------------------------------------------------------------------------
__global__ __launch_bounds__(256)
void conv_silu(const bf16* __restrict__ xz, const float* __restrict__ w,
               const float* __restrict__ bias, bf16* __restrict__ dx, int rev)
{
    const int idx = blockIdx.x * 256 + threadIdx.x;   // over M_ROWS * D_INNER
    const int d = idx & (D_INNER - 1);
    const int m = idx >> 10;
    const int b = m >> 12;
    const int t = m & (L_SEQ - 1);

    const bf16* xbase = xz + (size_t)b * L_SEQ * 2048 + d;
    float s = bias[d];
#pragma unroll
    for (int k = 0; k < 4; ++k) {
        const int src = t - 3 + k;
        if (src >= 0) {
            const int sm = rev ? (L_SEQ - 1 - src) : src;
            s += w[d * 4 + k] * __bfloat162float(xbase[(size_t)sm * 2048]);
        }
    }
    dx[(size_t)idx * 2 + 1] = __float2bfloat16(silu_f(s));
}

// ---------------------------------------------------------------------------
// Chunked selective scan, phase A: per (b,chunk,d) evolve h[16] from 0;
// emit chunk-final hF and S=sum(dt). Block 1024 = thread per d. Grid (NC,B).
// ---------------------------------------------------------------------------
__global__ __launch_bounds__(1024)
void scan_a(const unsigned int* __restrict__ dx, const float* __restrict__ dbl,
            const float* __restrict__ Alog, float* __restrict__ hF,
            float* __restrict__ Ssum)
{
    const int d = threadIdx.x;
    const int c = blockIdx.x;
    const int b = blockIdx.y;

    __shared__ float Bsh[CHK][16];
    {
        const int tl = d >> 4, nl = d & 15;
        Bsh[tl][nl] = dbl[((size_t)b * L_SEQ + c * CHK + tl) * 64 + DT_RANK + nl];
    }
    __syncthreads();

    float Acoef[16];
#pragma unroll
    for (int n = 0; n < 16; ++n) Acoef[n] = -__expf(Alog[d * 16 + n]);

    float h[16];
#pragma unroll
    for (int n = 0; n < 16; ++n) h[n] = 0.0f;
    float S = 0.0f;

    const unsigned int* dxp = dx + ((size_t)b * L_SEQ + c * CHK) * 1024 + d;
    unsigned int v = dxp[0];
    for (int t = 0; t < CHK; ++t) {
        const unsigned int vn = (t + 1 < CHK) ? dxp[(size_t)(t + 1) * 1024] : 0u;
        const float dt = __uint_as_float(v << 16);
        const float xv = __uint_as_float(v & 0xffff0000u);
        S += dt;
        const float dtx = dt * xv;
#pragma unroll
        for (int n = 0; n < 16; ++n)
            h[n] = fmaf(__expf(dt * Acoef[n]), h[n], dtx * Bsh[t][n]);
        v = vn;
    }

    float* hp = hF + (((size_t)(b * NC + c) * 1024 + d) << 4);
#pragma unroll
    for (int n = 0; n < 16; ++n) hp[n] = h[n];
    Ssum[(size_t)(b * NC + c) * 1024 + d] = S;
}

// ---------------------------------------------------------------------------
// Phase B: sequential combine over chunks; hF becomes each chunk's true
// initial state.
// ---------------------------------------------------------------------------
__global__ __launch_bounds__(256)
void scan_b(float* __restrict__ hF, const float* __restrict__ Ssum,
            const float* __restrict__ Alog)
{
    const int idx = blockIdx.x * 256 + threadIdx.x;   // B*D*16
    const int n  = idx & 15;
    const int dn = idx >> 4;
    const int d  = dn & (D_INNER - 1);
    const int b  = dn >> 10;

    const float Acoef = -__expf(Alog[d * 16 + n]);
    float H = 0.0f;
    for (int c = 0; c < NC; ++c) {
        const size_t base = (size_t)(b * NC + c) * 1024 + d;
        const float S = Ssum[base];
        float* hp = hF + (base << 4) + n;
        const float hOld = *hp;
        *hp = H;
        H = fmaf(__expf(Acoef * S), H, hOld);
    }
}

// ---------------------------------------------------------------------------
// Phase C: re-run chunk from true h_init; fused D*x + silu(z) gate; rev maps
// back to original time order; acc=1 accumulates (branch r into yfr).
// ---------------------------------------------------------------------------
__global__ __launch_bounds__(1024)
void scan_c(const unsigned int* __restrict__ dx, const float* __restrict__ dbl,
            const float* __restrict__ hF, const float* __restrict__ Alog,
            const float* __restrict__ Dp, const bf16* __restrict__ xz,
            bf16* __restrict__ yout, int rev, int acc)
{
    const int d = threadIdx.x;
    const int c = blockIdx.x;
    const int b = blockIdx.y;

    __shared__ float Bsh[CHK][16];
    __shared__ float Csh[CHK][16];
    {
        const int tl = d >> 4, nl = d & 15;
        const size_t rb = ((size_t)b * L_SEQ + c * CHK + tl) * 64;
        Bsh[tl][nl] = dbl[rb + DT_RANK + nl];
        Csh[tl][nl] = dbl[rb + DT_RANK + D_STATE + nl];
    }
    __syncthreads();

    float Acoef[16];
#pragma unroll
    for (int n = 0; n < 16; ++n) Acoef[n] = -__expf(Alog[d * 16 + n]);
    const float Dd = Dp[d];

    float h[16];
    {
        const float* hp = hF + (((size_t)(b * NC + c) * 1024 + d) << 4);
#pragma unroll
        for (int n = 0; n < 16; ++n) h[n] = hp[n];
    }

    const unsigned int* dxp = dx + ((size_t)b * L_SEQ + c * CHK) * 1024 + d;
    const bf16* z_base = xz + (size_t)b * L_SEQ * 2048 + D_INNER + d;
    bf16* y_base = yout + (size_t)b * L_SEQ * D_INNER + d;

    unsigned int v = dxp[0];
    for (int t = 0; t < CHK; ++t) {
        const unsigned int vn = (t + 1 < CHK) ? dxp[(size_t)(t + 1) * 1024] : 0u;
        const float dt = __uint_as_float(v << 16);
        const float xv = __uint_as_float(v & 0xffff0000u);
        const float dtx = dt * xv;
        float y = 0.0f;
#pragma unroll
        for (int n = 0; n < 16; ++n) {
            h[n] = fmaf(__expf(dt * Acoef[n]), h[n], dtx * Bsh[t][n]);
            y = fmaf(h[n], Csh[t][n], y);
        }
        const int tg = c * CHK + t;
        const int tm = rev ? (L_SEQ - 1 - tg) : tg;
        const float z = __bfloat162float(z_base[(size_t)tm * 2048]);
        float yo = (y + Dd * xv) * silu_f(z);
        const size_t oi = (size_t)tm * D_INNER;
        if (acc) yo += __bfloat162float(y_base[oi]);
        y_base[oi] = __float2bfloat16(yo);
        v = vn;
    }
}

// ---------------------------------------------------------------------------
extern "C" void kernel_launch(void* const* d_in, const int* in_sizes, int n_in,
                              void* d_out, int out_size, void* d_ws, size_t ws_size,
                              hipStream_t stream)
{
    const float* hs    = (const float*)d_in[0];
    const float* ahs   = (const float*)d_in[1];
    const float* in_w  = (const float*)d_in[2];
    const float* in_gw = (const float*)d_in[3];
    const float* convw[3] = {(const float*)d_in[4], (const float*)d_in[6], (const float*)d_in[8]};
    const float* convb[3] = {(const float*)d_in[5], (const float*)d_in[7], (const float*)d_in[9]};
    const float* xproj[3] = {(const float*)d_in[10], (const float*)d_in[11], (const float*)d_in[12]};
    const float* dtw[3]   = {(const float*)d_in[13], (const float*)d_in[15], (const float*)d_in[17]};
    const float* dtb[3]   = {(const float*)d_in[14], (const float*)d_in[16], (const float*)d_in[18]};
    const float* Alog[3]  = {(const float*)d_in[19], (const float*)d_in[20], (const float*)d_in[21]};
    const float* Dp[3]    = {(const float*)d_in[22], (const float*)d_in[23], (const float*)d_in[24]};
    const float* out_w = (const float*)d_in[25];

    // Workspace (~228 MB):
    unsigned short* regA = (unsigned short*)d_ws;                    // M*2048 bf16 (axz then xz)
    float* dbl  = (float*)(regA + (size_t)M_ROWS * 2048);            // M*64 f32
    unsigned int* dx = (unsigned int*)(dbl + (size_t)M_ROWS * 64);   // M*1024 u32 {dt,x}
    unsigned short* yfr = (unsigned short*)(dx + (size_t)M_ROWS * 1024);
    unsigned short* yg  = yfr + (size_t)M_ROWS * 1024;
    float* hF   = (float*)(yg + (size_t)M_ROWS * 1024);              // B*NC*1024*16 f32
    float* Ssum = hF + (size_t)B_SZ * NC * 1024 * 16;                // B*NC*1024 f32
    unsigned short* dtin = (unsigned short*)(Ssum + (size_t)B_SZ * NC * 1024); // M*32 bf16
    unsigned short* wbig = dtin + (size_t)M_ROWS * 32;               // 2048*512 bf16
    unsigned short* wout = wbig + (size_t)2048 * 512;                // 512*1024 bf16
    unsigned short* wxp  = wout + (size_t)512 * 1024;                // 64*1024 bf16
    unsigned short* wdt  = wxp + (size_t)64 * 1024;                  // 1024*32 bf16

    const dim3 blk(256);
    const int order[3] = {2, 0, 1};   // g, f, r

    // axz = ahs @ in_proj_g^T  (f32 A staged->bf16, MFMA)
    cvt_bf16<<<dim3(2048 * 512 / 1024), blk, 0, stream>>>(in_gw, wbig, 2048 * 512);
    gemm_mfma<128,128,64,4,4,1,0,1,0><<<dim3(16, 128), blk, 0, stream>>>(
        ahs, nullptr, wbig, nullptr, regA, nullptr, D_MODEL, D_MODEL, D_MODEL, 2048);

    for (int oi = 0; oi < 3; ++oi) {
        const int br = order[oi];
        const int rev  = (br == 1) ? 1 : 0;
        const int accf = (br == 1) ? 1 : 0;
        unsigned short* ybuf = (br == 2) ? yg : yfr;

        if (br == 0) {
            cvt_bf16<<<dim3(2048 * 512 / 1024), blk, 0, stream>>>(in_w, wbig, 2048 * 512);
            gemm_mfma<128,128,64,4,4,1,0,1,0><<<dim3(16, 128), blk, 0, stream>>>(
                hs, nullptr, wbig, nullptr, regA, nullptr, D_MODEL, D_MODEL, D_MODEL, 2048);
        }

        conv_silu<<<dim3((M_ROWS * D_INNER) / 256), blk, 0, stream>>>(
            (const bf16*)regA, convw[br], convb[br], (bf16*)dx, rev);

        // dbl = x @ xproj^T (A = x slot of dx) ; dual-write bf16 dtin (cols<32)
        cvt_bf16<<<dim3(64 * 1024 / 1024), blk, 0, stream>>>(xproj[br], wxp, 64 * 1024);
        gemm_mfma<64,64,64,2,2,2,2,1,1><<<dim3(1, 256), blk, 0, stream>>>(
            dx, nullptr, wxp, nullptr, dbl, dtin, D_INNER, D_INNER, D_INNER, 64);

        // dt = softplus(dtin @ dtw^T + dtb) -> dt slot of dx (stride 2)
        cvt_bf16<<<dim3(1024 * 32 / 1024), blk, 0, stream>>>(dtw[br], wdt, 1024 * 32);
        gemm_mfma<128,128,32,4,4,0,1,2,0><<<dim3(8, 128), blk, 0, stream>>>(
            dtin, nullptr, wdt, dtb[br], dx, nullptr, DT_RANK, DT_RANK, DT_RANK, D_INNER);

        scan_a<<<dim3(NC, B_SZ), dim3(1024), 0, stream>>>(dx, dbl, Alog[br], hF, Ssum);
        scan_b<<<dim3((B_SZ * D_INNER * 16) / 256), blk, 0, stream>>>(hF, Ssum, Alog[br]);
        scan_c<<<dim3(NC, B_SZ), dim3(1024), 0, stream>>>(
            dx, dbl, hF, Alog[br], Dp[br], (const bf16*)regA, (bf16*)ybuf, rev, accf);
    }

    // out = ((y_f + y_r) * silu(y_g)) @ out_proj^T  (gated A, MFMA, f32 C)
    cvt_bf16<<<dim3(512 * 1024 / 1024), blk, 0, stream>>>(out_w, wout, 512 * 1024);
    gemm_mfma<128,128,64,4,4,3,0,1,1><<<dim3(4, 128), blk, 0, stream>>>(
        yfr, yg, wout, nullptr, d_out, nullptr, D_INNER, D_INNER, D_INNER, D_MODEL);
}

// Round 8
// 1133.054 us; speedup vs baseline: 10.6156x; 1.1159x over previous
//
#include <hip/hip_runtime.h>
#include <hip/hip_bf16.h>
#include <math.h>

#define L_SEQ 4096
#define B_SZ 4
#define D_MODEL 512
#define D_INNER 1024
#define DT_RANK 32
#define D_STATE 16
#define M_ROWS (B_SZ * L_SEQ)   // 16384
#define NC 64                    // chunks per sequence
#define CHK (L_SEQ / NC)         // 64 steps per chunk

typedef __hip_bfloat16 bf16;
typedef __bf16 bf16x8 __attribute__((ext_vector_type(8)));
typedef float f32x4 __attribute__((ext_vector_type(4)));
struct us8 { ushort4 a, b; };    // 16-byte chunk of 8 bf16 bit patterns

// ---- bf16 bit conversions -------------------------------------------------
__device__ __forceinline__ unsigned short f2us(float f) {
    union { bf16 h; unsigned short u; } t;
    t.h = __float2bfloat16(f);
    return t.u;
}
__device__ __forceinline__ float us2f(unsigned short u) {
    union { bf16 h; unsigned short u; } t;
    t.u = u;
    return __bfloat162float(t.h);
}

// ---- hardened transcendentals ---------------------------------------------
__device__ __forceinline__ float silu_f(float x) {
    const float xc = fminf(fmaxf(x, -60.0f), 60.0f);
    return x / (1.0f + __expf(-xc));
}
__device__ __forceinline__ float softplus_f(float x) {
    if (x > 20.0f) return x;
    if (x < -20.0f) return __expf(x);
    return log1pf(__expf(x));
}

// ---------------------------------------------------------------------------
// Fused multi-segment f32 -> bf16 conversion (one dispatch for many tensors).
// Each thread converts one 4-elem vector; segment found by linear scan.
// ---------------------------------------------------------------------------
struct CvtArgs {
    const float* src[9];
    unsigned short* dst[9];
    unsigned int vend[9];   // cumulative vec4 counts
    int nseg;
};
__global__ __launch_bounds__(256)
void cvt_multi(CvtArgs a)
{
    const unsigned int v = blockIdx.x * 256 + threadIdx.x;
    if (v >= a.vend[a.nseg - 1]) return;
    int s = 0;
    unsigned int vstart = 0;
    while (v >= a.vend[s]) { vstart = a.vend[s]; ++s; }
    const size_t lv = (size_t)(v - vstart) * 4;
    const float4 f = *(const float4*)(a.src[s] + lv);
    ushort4 o;
    o.x = f2us(f.x); o.y = f2us(f.y); o.z = f2us(f.z); o.w = f2us(f.w);
    *(ushort4*)(a.dst[s] + lv) = o;
}

// ---------------------------------------------------------------------------
// MFMA bf16 "NT" GEMM v2: C[m,n] = sum_k A[m,k]*W[n,k], f32 accumulate.
// Staging via global_load_lds (16B DMA, no VGPR round-trip) into an
// XOR-swizzled LDS layout: 16B chunk (row, c) stored at c' = c ^ (row&SWM).
// DMA writes are conflict-free (lane i -> base + i*16); fragment
// ds_read_b128 spreads all 32 banks (2-way aliasing max = free).
// GATED==1: A element = A*silu(A2), staged by VALU (same swizzle).
// EPI: 0 none; 1 softplus(acc+bias[n]); 2 dual write f32 C + bf16 C2 (n<32).
// CT : 0 C bf16, 1 C f32. Block 256 = 4 waves, wave tile (WY*16)x(WX*16).
// ---------------------------------------------------------------------------
template<int BM, int BN, int BK, int WY, int WX, int GATED, int EPI, int CT>
__global__ __launch_bounds__(256)
void gemm_mfma(const unsigned short* __restrict__ A,
               const unsigned short* __restrict__ A2,
               const unsigned short* __restrict__ W,
               const float* __restrict__ bias,
               void* __restrict__ Cp, unsigned short* __restrict__ C2p,
               int K, int lda, int ldb, int ldc)
{
    constexpr int CPR = BK / 8;        // 16B chunks per LDS row
    constexpr int SWM = CPR - 1;
    constexpr int RPW = 64 / CPR;      // rows per wave per DMA pass
    constexpr int NPA = BM / (4 * RPW);
    constexpr int NPB = BN / (4 * RPW);
    constexpr int WGX = BN / (WX * 16);
    static_assert(WGX * (BM / (WY * 16)) == 4, "4 waves");
    __shared__ unsigned short As[BM * BK];
    __shared__ unsigned short Bs[BN * BK];

    const int tid  = threadIdx.x;
    const int lane = tid & 63;
    const int wave = tid >> 6;
    const int wx = wave % WGX, wy = wave / WGX;
    const int l15 = lane & 15, quad = lane >> 4;
    const long row0 = (long)blockIdx.y * BM;
    const long col0 = (long)blockIdx.x * BN;

    // DMA lane mapping: lane -> (row-in-pass, swizzled source chunk)
    const int rin = lane / CPR;
    const int gc  = (lane % CPR) ^ (rin & SWM);

    f32x4 acc[WY][WX];
#pragma unroll
    for (int i = 0; i < WY; ++i)
#pragma unroll
        for (int j = 0; j < WX; ++j) acc[i][j] = (f32x4){0.f, 0.f, 0.f, 0.f};

    for (int k0 = 0; k0 < K; k0 += BK) {
        if (GATED == 0) {
#pragma unroll
            for (int p = 0; p < NPA; ++p) {
                const int rb = (p * 4 + wave) * RPW;
                const unsigned short* gp = A + (row0 + rb + rin) * (long)lda + k0 + gc * 8;
                const int lb = __builtin_amdgcn_readfirstlane(rb * BK);
                __builtin_amdgcn_global_load_lds(
                    (const __attribute__((address_space(1))) void*)gp,
                    (__attribute__((address_space(3))) void*)(As + lb), 16, 0, 0);
            }
        } else {
#pragma unroll
            for (int v = 0; v < BM * BK / 2048; ++v) {
                const int e = (v * 256 + tid) * 8;
                const int r = e / BK, c = (e % BK) / 8;
                const long off = (row0 + r) * (long)lda + k0 + c * 8;
                const us8 ta = *(const us8*)(A + off);
                const us8 tg = *(const us8*)(A2 + off);
                us8 t;
                t.a.x = f2us(us2f(ta.a.x) * silu_f(us2f(tg.a.x)));
                t.a.y = f2us(us2f(ta.a.y) * silu_f(us2f(tg.a.y)));
                t.a.z = f2us(us2f(ta.a.z) * silu_f(us2f(tg.a.z)));
                t.a.w = f2us(us2f(ta.a.w) * silu_f(us2f(tg.a.w)));
                t.b.x = f2us(us2f(ta.b.x) * silu_f(us2f(tg.b.x)));
                t.b.y = f2us(us2f(ta.b.y) * silu_f(us2f(tg.b.y)));
                t.b.z = f2us(us2f(ta.b.z) * silu_f(us2f(tg.b.z)));
                t.b.w = f2us(us2f(ta.b.w) * silu_f(us2f(tg.b.w)));
                *(us8*)&As[r * BK + ((c ^ (r & SWM)) * 8)] = t;
            }
        }
#pragma unroll
        for (int p = 0; p < NPB; ++p) {
            const int rb = (p * 4 + wave) * RPW;
            const unsigned short* gp = W + (col0 + rb + rin) * (long)ldb + k0 + gc * 8;
            const int lb = __builtin_amdgcn_readfirstlane(rb * BK);
            __builtin_amdgcn_global_load_lds(
                (const __attribute__((address_space(1))) void*)gp,
                (__attribute__((address_space(3))) void*)(Bs + lb), 16, 0, 0);
        }
        __syncthreads();   // drains vmcnt (DMA) + lgkmcnt before LDS reads

#pragma unroll
        for (int kk = 0; kk < BK / 32; ++kk) {
            bf16x8 aF[WY], bF[WX];
#pragma unroll
            for (int i = 0; i < WY; ++i) {
                const int r  = wy * WY * 16 + i * 16 + l15;
                const int kc = (kk * 4 + quad) ^ (r & SWM);
                aF[i] = *(const bf16x8*)&As[r * BK + kc * 8];
            }
#pragma unroll
            for (int j = 0; j < WX; ++j) {
                const int r  = wx * WX * 16 + j * 16 + l15;
                const int kc = (kk * 4 + quad) ^ (r & SWM);
                bF[j] = *(const bf16x8*)&Bs[r * BK + kc * 8];
            }
#pragma unroll
            for (int i = 0; i < WY; ++i)
#pragma unroll
                for (int j = 0; j < WX; ++j)
                    acc[i][j] = __builtin_amdgcn_mfma_f32_16x16x32_bf16(
                        aF[i], bF[j], acc[i][j], 0, 0, 0);
        }
        __syncthreads();
    }

    // ---- epilogue: lane holds rows quad*4+r, col l15 of each 16x16 tile ----
#pragma unroll
    for (int i = 0; i < WY; ++i)
#pragma unroll
        for (int j = 0; j < WX; ++j) {
            const long mb = row0 + wy * WY * 16 + i * 16 + quad * 4;
            const long n  = col0 + wx * WX * 16 + j * 16 + l15;
            const float bv = (EPI == 1) ? bias[n] : 0.0f;
#pragma unroll
            for (int r = 0; r < 4; ++r) {
                float val = acc[i][j][r];
                if (EPI == 1) val = softplus_f(val + bv);
                const long off = (mb + r) * (long)ldc + n;
                if (CT == 0) ((unsigned short*)Cp)[off] = f2us(val);
                else         ((float*)Cp)[off] = val;
                if (EPI == 2 && n < DT_RANK) C2p[(mb + r) * DT_RANK + n] = f2us(val);
            }
        }
}

// ---------------------------------------------------------------------------
// Depthwise causal conv1d (k=4) + bias + SiLU, 8 d-elements per thread.
// Output xb contiguous bf16 (scan order). rev=1: flipped-time read.
// ---------------------------------------------------------------------------
__global__ __launch_bounds__(256)
void conv_silu8(const unsigned short* __restrict__ xz, const float* __restrict__ w,
                const float* __restrict__ bias, unsigned short* __restrict__ xb, int rev)
{
    const int idx = blockIdx.x * 256 + threadIdx.x;   // over M_ROWS * 128
    const int g = idx & 127;
    const int m = idx >> 7;
    const int b = m >> 12;
    const int t = m & (L_SEQ - 1);
    const int d = g * 8;

    float s[8];
    {
        const float4 b0 = *(const float4*)(bias + d);
        const float4 b1 = *(const float4*)(bias + d + 4);
        s[0] = b0.x; s[1] = b0.y; s[2] = b0.z; s[3] = b0.w;
        s[4] = b1.x; s[5] = b1.y; s[6] = b1.z; s[7] = b1.w;
    }
    float4 wv[8];
#pragma unroll
    for (int j = 0; j < 8; ++j) wv[j] = *(const float4*)(w + (d + j) * 4);

    const unsigned short* xbase = xz + (size_t)b * L_SEQ * 2048 + d;
#pragma unroll
    for (int k = 0; k < 4; ++k) {
        const int src = t - 3 + k;
        if (src >= 0) {
            const int sm = rev ? (L_SEQ - 1 - src) : src;
            const us8 xv = *(const us8*)(xbase + (size_t)sm * 2048);
            const float tap[8] = {us2f(xv.a.x), us2f(xv.a.y), us2f(xv.a.z), us2f(xv.a.w),
                                  us2f(xv.b.x), us2f(xv.b.y), us2f(xv.b.z), us2f(xv.b.w)};
#pragma unroll
            for (int j = 0; j < 8; ++j) {
                const float wk = (k == 0) ? wv[j].x : (k == 1) ? wv[j].y
                               : (k == 2) ? wv[j].z : wv[j].w;
                s[j] = fmaf(wk, tap[j], s[j]);
            }
        }
    }
    us8 o;
    o.a.x = f2us(silu_f(s[0])); o.a.y = f2us(silu_f(s[1]));
    o.a.z = f2us(silu_f(s[2])); o.a.w = f2us(silu_f(s[3]));
    o.b.x = f2us(silu_f(s[4])); o.b.y = f2us(silu_f(s[5]));
    o.b.z = f2us(silu_f(s[6])); o.b.w = f2us(silu_f(s[7]));
    *(us8*)(xb + (size_t)m * 1024 + d) = o;
}

// ---------------------------------------------------------------------------
// Chunked selective scan, phase A: per (b,chunk,d) evolve h[16] from 0;
// emit chunk-final hF and S=sum(dt). Block 1024 = thread per d. Grid (NC,B).
// ---------------------------------------------------------------------------
__global__ __launch_bounds__(1024)
void scan_a(const unsigned short* __restrict__ dtq, const unsigned short* __restrict__ xq,
            const float* __restrict__ dbl, const float* __restrict__ Alog,
            float* __restrict__ hF, float* __restrict__ Ssum)
{
    const int d = threadIdx.x;
    const int c = blockIdx.x;
    const int b = blockIdx.y;

    __shared__ float Bsh[CHK][16];
    {
        const int tl = d >> 4, nl = d & 15;
        Bsh[tl][nl] = dbl[((size_t)b * L_SEQ + c * CHK + tl) * 64 + DT_RANK + nl];
    }
    __syncthreads();

    float Acoef[16];
#pragma unroll
    for (int n = 0; n < 16; ++n) Acoef[n] = -__expf(Alog[d * 16 + n]);

    float h[16];
#pragma unroll
    for (int n = 0; n < 16; ++n) h[n] = 0.0f;
    float S = 0.0f;

    const size_t base = ((size_t)b * L_SEQ + c * CHK) * 1024 + d;
    const unsigned short* dtp = dtq + base;
    const unsigned short* xp  = xq + base;
    unsigned short vd = dtp[0], vx = xp[0];
    for (int t = 0; t < CHK; ++t) {
        unsigned short vd2 = 0, vx2 = 0;
        if (t + 1 < CHK) {
            vd2 = dtp[(size_t)(t + 1) * 1024];
            vx2 = xp[(size_t)(t + 1) * 1024];
        }
        const float dt = us2f(vd);
        const float xv = us2f(vx);
        S += dt;
        const float dtx = dt * xv;
#pragma unroll
        for (int n = 0; n < 16; ++n)
            h[n] = fmaf(__expf(dt * Acoef[n]), h[n], dtx * Bsh[t][n]);
        vd = vd2; vx = vx2;
    }

    float* hp = hF + (((size_t)(b * NC + c) * 1024 + d) << 4);
#pragma unroll
    for (int n = 0; n < 16; ++n) hp[n] = h[n];
    Ssum[(size_t)(b * NC + c) * 1024 + d] = S;
}

// ---------------------------------------------------------------------------
// Phase B: sequential combine over chunks; hF becomes each chunk's true
// initial state.
// ---------------------------------------------------------------------------
__global__ __launch_bounds__(256)
void scan_b(float* __restrict__ hF, const float* __restrict__ Ssum,
            const float* __restrict__ Alog)
{
    const int idx = blockIdx.x * 256 + threadIdx.x;   // B*D*16
    const int n  = idx & 15;
    const int dn = idx >> 4;
    const int d  = dn & (D_INNER - 1);
    const int b  = dn >> 10;

    const float Acoef = -__expf(Alog[d * 16 + n]);
    float H = 0.0f;
    for (int c = 0; c < NC; ++c) {
        const size_t base = (size_t)(b * NC + c) * 1024 + d;
        const float S = Ssum[base];
        float* hp = hF + (base << 4) + n;
        const float hOld = *hp;
        *hp = H;
        H = fmaf(__expf(Acoef * S), H, hOld);
    }
}

// ---------------------------------------------------------------------------
// Phase C: re-run chunk from true h_init; fused D*x + silu(z) gate; rev maps
// back to original time order; acc=1 accumulates (branch r into yfr).
// ---------------------------------------------------------------------------
__global__ __launch_bounds__(1024)
void scan_c(const unsigned short* __restrict__ dtq, const unsigned short* __restrict__ xq,
            const float* __restrict__ dbl, const float* __restrict__ hF,
            const float* __restrict__ Alog, const float* __restrict__ Dp,
            const unsigned short* __restrict__ xz, unsigned short* __restrict__ yout,
            int rev, int acc)
{
    const int d = threadIdx.x;
    const int c = blockIdx.x;
    const int b = blockIdx.y;

    __shared__ float Bsh[CHK][16];
    __shared__ float Csh[CHK][16];
    {
        const int tl = d >> 4, nl = d & 15;
        const size_t rb = ((size_t)b * L_SEQ + c * CHK + tl) * 64;
        Bsh[tl][nl] = dbl[rb + DT_RANK + nl];
        Csh[tl][nl] = dbl[rb + DT_RANK + D_STATE + nl];
    }
    __syncthreads();

    float Acoef[16];
#pragma unroll
    for (int n = 0; n < 16; ++n) Acoef[n] = -__expf(Alog[d * 16 + n]);
    const float Dd = Dp[d];

    float h[16];
    {
        const float* hp = hF + (((size_t)(b * NC + c) * 1024 + d) << 4);
#pragma unroll
        for (int n = 0; n < 16; ++n) h[n] = hp[n];
    }

    const size_t base = ((size_t)b * L_SEQ + c * CHK) * 1024 + d;
    const unsigned short* dtp = dtq + base;
    const unsigned short* xp  = xq + base;
    const unsigned short* z_base = xz + (size_t)b * L_SEQ * 2048 + D_INNER + d;
    unsigned short* y_base = yout + (size_t)b * L_SEQ * D_INNER + d;

    unsigned short vd = dtp[0], vx = xp[0];
    for (int t = 0; t < CHK; ++t) {
        unsigned short vd2 = 0, vx2 = 0;
        if (t + 1 < CHK) {
            vd2 = dtp[(size_t)(t + 1) * 1024];
            vx2 = xp[(size_t)(t + 1) * 1024];
        }
        const float dt = us2f(vd);
        const float xv = us2f(vx);
        const float dtx = dt * xv;
        float y = 0.0f;
#pragma unroll
        for (int n = 0; n < 16; ++n) {
            h[n] = fmaf(__expf(dt * Acoef[n]), h[n], dtx * Bsh[t][n]);
            y = fmaf(h[n], Csh[t][n], y);
        }
        const int tg = c * CHK + t;
        const int tm = rev ? (L_SEQ - 1 - tg) : tg;
        const float z = us2f(z_base[(size_t)tm * 2048]);
        float yo = (y + Dd * xv) * silu_f(z);
        const size_t oi = (size_t)tm * D_INNER;
        if (acc) yo += us2f(y_base[oi]);
        y_base[oi] = f2us(yo);
        vd = vd2; vx = vx2;
    }
}

// ---------------------------------------------------------------------------
extern "C" void kernel_launch(void* const* d_in, const int* in_sizes, int n_in,
                              void* d_out, int out_size, void* d_ws, size_t ws_size,
                              hipStream_t stream)
{
    const float* hs    = (const float*)d_in[0];
    const float* ahs   = (const float*)d_in[1];
    const float* in_w  = (const float*)d_in[2];
    const float* in_gw = (const float*)d_in[3];
    const float* convw[3] = {(const float*)d_in[4], (const float*)d_in[6], (const float*)d_in[8]};
    const float* convb[3] = {(const float*)d_in[5], (const float*)d_in[7], (const float*)d_in[9]};
    const float* xproj[3] = {(const float*)d_in[10], (const float*)d_in[11], (const float*)d_in[12]};
    const float* dtw[3]   = {(const float*)d_in[13], (const float*)d_in[15], (const float*)d_in[17]};
    const float* dtbias[3]= {(const float*)d_in[14], (const float*)d_in[16], (const float*)d_in[18]};
    const float* Alog[3]  = {(const float*)d_in[19], (const float*)d_in[20], (const float*)d_in[21]};
    const float* Dp[3]    = {(const float*)d_in[22], (const float*)d_in[23], (const float*)d_in[24]};
    const float* out_w = (const float*)d_in[25];

    // Workspace (~228 MB, matches round-7 proven size):
    unsigned short* regA = (unsigned short*)d_ws;                    // M*2048 (axz then xz)
    float* dbl  = (float*)(regA + (size_t)M_ROWS * 2048);            // M*64 f32
    unsigned short* xb  = (unsigned short*)(dbl + (size_t)M_ROWS * 64); // M*1024
    unsigned short* dtv = xb  + (size_t)M_ROWS * 1024;               // M*1024
    unsigned short* yfr = dtv + (size_t)M_ROWS * 1024;               // M*1024 (first half = inb)
    unsigned short* yg  = yfr + (size_t)M_ROWS * 1024;               // M*1024
    float* hF   = (float*)(yg + (size_t)M_ROWS * 1024);              // B*NC*1024*16 f32
    float* Ssum = hF + (size_t)B_SZ * NC * 1024 * 16;                // B*NC*1024 f32
    unsigned short* dtin = (unsigned short*)(Ssum + (size_t)B_SZ * NC * 1024); // M*32
    unsigned short* wbig = dtin + (size_t)M_ROWS * 32;               // 2048*512
    unsigned short* wout = wbig + (size_t)2048 * 512;                // 512*1024
    unsigned short* wxpb = wout + (size_t)512 * 1024;                // 3 x 64*1024
    unsigned short* wdtb = wxpb + (size_t)3 * 64 * 1024;             // 3 x 1024*32
    unsigned short* inb  = yfr;   // 16 MB staging for bf16(ahs)/bf16(hs)

    const dim3 blk(256);

    // ---- cvt1: ahs + in_gw + out_w + xproj x3 + dtw x3 (one dispatch) ----
    {
        CvtArgs a;
        unsigned int acc = 0;
        const float* srcs[9] = {ahs, in_gw, out_w, xproj[0], xproj[1], xproj[2],
                                dtw[0], dtw[1], dtw[2]};
        unsigned short* dsts[9] = {inb, wbig, wout,
                                   wxpb, wxpb + 64 * 1024, wxpb + 2 * 64 * 1024,
                                   wdtb, wdtb + 1024 * 32, wdtb + 2 * 1024 * 32};
        const unsigned int sz[9] = {M_ROWS * 512u, 2048u * 512u, 512u * 1024u,
                                    64u * 1024u, 64u * 1024u, 64u * 1024u,
                                    1024u * 32u, 1024u * 32u, 1024u * 32u};
        for (int i = 0; i < 9; ++i) {
            a.src[i] = srcs[i]; a.dst[i] = dsts[i];
            acc += sz[i] / 4; a.vend[i] = acc;
        }
        a.nseg = 9;
        cvt_multi<<<dim3((acc + 255) / 256), blk, 0, stream>>>(a);
    }

    const int order[3] = {2, 0, 1};   // g, f, r

    // axz = bf16(ahs) @ in_proj_g^T -> regA
    gemm_mfma<128,128,64,4,4,0,0,0><<<dim3(16, 128), blk, 0, stream>>>(
        inb, nullptr, wbig, nullptr, regA, nullptr, D_MODEL, D_MODEL, D_MODEL, 2048);

    for (int oi = 0; oi < 3; ++oi) {
        const int br = order[oi];
        const int rev  = (br == 1) ? 1 : 0;
        const int accf = (br == 1) ? 1 : 0;
        unsigned short* ybuf = (br == 2) ? yg : yfr;

        if (br == 0) {
            // cvt2: hs + in_w into the (now free) inb/wbig buffers
            CvtArgs a;
            a.src[0] = hs;   a.dst[0] = inb;  a.vend[0] = M_ROWS * 512u / 4;
            a.src[1] = in_w; a.dst[1] = wbig; a.vend[1] = a.vend[0] + 2048u * 512u / 4;
            a.nseg = 2;
            cvt_multi<<<dim3((a.vend[1] + 255) / 256), blk, 0, stream>>>(a);
            gemm_mfma<128,128,64,4,4,0,0,0><<<dim3(16, 128), blk, 0, stream>>>(
                inb, nullptr, wbig, nullptr, regA, nullptr, D_MODEL, D_MODEL, D_MODEL, 2048);
        }

        conv_silu8<<<dim3(M_ROWS * 128 / 256), blk, 0, stream>>>(
            regA, convw[br], convb[br], xb, rev);

        // dbl = xb @ xproj^T (f32) + dual-write bf16 dtin (cols<32)
        gemm_mfma<64,64,64,2,2,0,2,1><<<dim3(1, 256), blk, 0, stream>>>(
            xb, nullptr, wxpb + br * 64 * 1024, nullptr, dbl, dtin,
            D_INNER, D_INNER, D_INNER, 64);

        // dtv = softplus(dtin @ dtw^T + dtb), bf16 contiguous
        gemm_mfma<128,128,32,4,4,0,1,0><<<dim3(8, 128), blk, 0, stream>>>(
            dtin, nullptr, wdtb + br * 1024 * 32, dtbias[br], dtv, nullptr,
            DT_RANK, DT_RANK, DT_RANK, D_INNER);

        scan_a<<<dim3(NC, B_SZ), dim3(1024), 0, stream>>>(dtv, xb, dbl, Alog[br], hF, Ssum);
        scan_b<<<dim3((B_SZ * D_INNER * 16) / 256), blk, 0, stream>>>(hF, Ssum, Alog[br]);
        scan_c<<<dim3(NC, B_SZ), dim3(1024), 0, stream>>>(
            dtv, xb, dbl, hF, Alog[br], Dp[br], regA, ybuf, rev, accf);
    }

    // out = ((y_f + y_r) * silu(y_g)) @ out_proj^T (gated A, f32 C)
    gemm_mfma<128,128,64,4,4,1,0,1><<<dim3(4, 128), blk, 0, stream>>>(
        yfr, yg, wout, nullptr, d_out, nullptr, D_INNER, D_INNER, D_INNER, D_MODEL);
}